// Round 1
// baseline (2717.954 us; speedup 1.0000x reference)
//
#include <hip/hip_runtime.h>

#define N_TOK 8192
#define HEADS 16
#define DIM 64
#define WIN 128

// ---------------- pooling: mean over S raw tokens per chunk ----------------
__global__ void pool_kernel(const float* __restrict__ k, const float* __restrict__ v,
                            float* __restrict__ kp, float* __restrict__ vp,
                            int S, int C) {
    int tid = blockIdx.x * blockDim.x + threadIdx.x;
    int total = HEADS * C * DIM;
    if (tid >= total) return;
    int t = tid & (DIM - 1);
    int c = (tid / DIM) % C;
    int h = tid / (DIM * C);
    size_t base = ((size_t)(h * N_TOK + c * S)) * DIM + t;
    float ks = 0.f, vs = 0.f;
    for (int r = 0; r < S; ++r) {
        ks += k[base + (size_t)r * DIM];
        vs += v[base + (size_t)r * DIM];
    }
    float inv = 1.0f / (float)S;
    kp[tid] = ks * inv;
    vp[tid] = vs * inv;
}

// ---------------- main attention: one wave (64 lanes) per 64 queries ----------------
__global__ __launch_bounds__(64) void attn_kernel(
    const float* __restrict__ q, const float* __restrict__ k, const float* __restrict__ v,
    const float* __restrict__ gam,
    const float* __restrict__ k1, const float* __restrict__ v1,
    const float* __restrict__ k2, const float* __restrict__ v2,
    const float* __restrict__ k3, const float* __restrict__ v3,
    float* __restrict__ out) {
    const int lane = threadIdx.x;                 // 0..63
    const int wid  = blockIdx.x;                  // 0..HEADS*N/64-1
    const int h    = wid / (N_TOK / 64);
    const int qb   = (wid % (N_TOK / 64)) * 64;
    const int i    = qb + lane;                   // this lane's query index
    const float scale = 0.125f;                   // 1/sqrt(64)

    const float g0 = gam[0], g1 = gam[1], g2 = gam[2], g3 = gam[3];

    // load q row into registers
    float qr[DIM];
    {
        const float4* q4 = (const float4*)q;
        size_t base = ((size_t)(h * N_TOK + i)) * (DIM / 4);
#pragma unroll
        for (int t = 0; t < DIM / 4; ++t) {
            float4 x = q4[base + t];
            qr[4 * t + 0] = x.x; qr[4 * t + 1] = x.y;
            qr[4 * t + 2] = x.z; qr[4 * t + 3] = x.w;
        }
    }

    float o[DIM];
#pragma unroll
    for (int t = 0; t < DIM; ++t) o[t] = 0.f;
    float m = -1e30f, l = 0.f;

    // one online-softmax step for one key row (wave-uniform krow/vrow)
    auto step = [&](const float4* __restrict__ krow, const float4* __restrict__ vrow,
                    float bias /*gamma*dist, per-lane*/, bool act) {
        float a0 = 0.f, a1 = 0.f, a2 = 0.f, a3 = 0.f;
#pragma unroll
        for (int t = 0; t < 16; t += 4) {
            float4 x0 = krow[t + 0], x1 = krow[t + 1], x2 = krow[t + 2], x3 = krow[t + 3];
            a0 += x0.x * qr[4*t + 0] + x0.y * qr[4*t + 1] + x0.z * qr[4*t + 2] + x0.w * qr[4*t + 3];
            a1 += x1.x * qr[4*t + 4] + x1.y * qr[4*t + 5] + x1.z * qr[4*t + 6] + x1.w * qr[4*t + 7];
            a2 += x2.x * qr[4*t + 8] + x2.y * qr[4*t + 9] + x2.z * qr[4*t +10] + x2.w * qr[4*t +11];
            a3 += x3.x * qr[4*t +12] + x3.y * qr[4*t +13] + x3.z * qr[4*t +14] + x3.w * qr[4*t +15];
        }
        float s = ((a0 + a1) + (a2 + a3)) * scale - bias;
        s = act ? s : -1e30f;
        if (__any(s > m)) {
            float mn = fmaxf(m, s);
            float sf = __expf(m - mn);          // m=-1e30 -> 0; unchanged -> 1
            float p  = act ? __expf(s - mn) : 0.f;
            m = mn;
            l = l * sf + p;
#pragma unroll
            for (int t = 0; t < 16; ++t) {
                float4 b = vrow[t];
                o[4*t + 0] = o[4*t + 0] * sf + p * b.x;
                o[4*t + 1] = o[4*t + 1] * sf + p * b.y;
                o[4*t + 2] = o[4*t + 2] * sf + p * b.z;
                o[4*t + 3] = o[4*t + 3] * sf + p * b.w;
            }
        } else {
            float p = act ? __expf(s - m) : 0.f;
            l += p;
#pragma unroll
            for (int t = 0; t < 16; ++t) {
                float4 b = vrow[t];
                o[4*t + 0] += p * b.x;
                o[4*t + 1] += p * b.y;
                o[4*t + 2] += p * b.z;
                o[4*t + 3] += p * b.w;
            }
        }
    };

    // ---- level 0: exact sliding window, newest key first ----
    {
        const float4* k4 = (const float4*)k;
        const float4* v4 = (const float4*)v;
        int jlo = qb - (WIN - 1); if (jlo < 0) jlo = 0;
        for (int j = qb + 63; j >= jlo; --j) {
            size_t base = ((size_t)(h * N_TOK + j)) * 16;
            int dist = i - j;
            bool act = (dist >= 0) && (dist <= WIN - 1);
            step(k4 + base, v4 + base, g0 * (float)dist, act);
        }
    }

    // ---- hierarchical levels, newest chunk first ----
    // level template: chunks of S raw tokens, C chunks, pooled arrays (H,C,64)
    {
        const int S = 8, C = 1024;
        int num = qb + 63 - (WIN - 1) - S;        // c <= (i - 127 - S)/S
        if (num >= 0) {
            int cmax = num / S;
            const float4* k4 = (const float4*)k1;
            const float4* v4 = (const float4*)v1;
            for (int c = cmax; c >= 0; --c) {
                size_t base = ((size_t)(h * C + c)) * 16;
                int jlast = c * S + S - 1;
                int dist = i - jlast;
                bool act = dist >= WIN;
                step(k4 + base, v4 + base, g1 * (float)dist, act);
            }
        }
    }
    {
        const int S = 64, C = 128;
        int num = qb + 63 - (WIN - 1) - S;
        if (num >= 0) {
            int cmax = num / S;
            const float4* k4 = (const float4*)k2;
            const float4* v4 = (const float4*)v2;
            for (int c = cmax; c >= 0; --c) {
                size_t base = ((size_t)(h * C + c)) * 16;
                int jlast = c * S + S - 1;
                int dist = i - jlast;
                bool act = dist >= WIN;
                step(k4 + base, v4 + base, g2 * (float)dist, act);
            }
        }
    }
    {
        const int S = 512, C = 16;
        int num = qb + 63 - (WIN - 1) - S;
        if (num >= 0) {
            int cmax = num / S;
            const float4* k4 = (const float4*)k3;
            const float4* v4 = (const float4*)v3;
            for (int c = cmax; c >= 0; --c) {
                size_t base = ((size_t)(h * C + c)) * 16;
                int jlast = c * S + S - 1;
                int dist = i - jlast;
                bool act = dist >= WIN;
                step(k4 + base, v4 + base, g3 * (float)dist, act);
            }
        }
    }

    // ---- write out: o / clip(l, 1e-8) ----
    float invl = 1.0f / fmaxf(l, 1e-8f);
    float4* o4 = (float4*)out;
    size_t base = ((size_t)(h * N_TOK + i)) * 16;
#pragma unroll
    for (int t = 0; t < 16; ++t) {
        float4 x;
        x.x = o[4*t + 0] * invl;
        x.y = o[4*t + 1] * invl;
        x.z = o[4*t + 2] * invl;
        x.w = o[4*t + 3] * invl;
        o4[base + t] = x;
    }
}

extern "C" void kernel_launch(void* const* d_in, const int* in_sizes, int n_in,
                              void* d_out, int out_size, void* d_ws, size_t ws_size,
                              hipStream_t stream) {
    const float* q   = (const float*)d_in[0];
    const float* k   = (const float*)d_in[1];
    const float* v   = (const float*)d_in[2];
    const float* gam = (const float*)d_in[3];
    float* out = (float*)d_out;

    // workspace layout (floats)
    float* ws = (float*)d_ws;
    const size_t n1 = (size_t)HEADS * 1024 * DIM;   // 1,048,576
    const size_t n2 = (size_t)HEADS * 128  * DIM;   // 131,072
    const size_t n3 = (size_t)HEADS * 16   * DIM;   // 16,384
    float* k1 = ws;
    float* v1 = k1 + n1;
    float* k2 = v1 + n1;
    float* v2 = k2 + n2;
    float* k3 = v2 + n2;
    float* v3 = k3 + n3;

    // pooling (all read raw k,v; independent of each other)
    {
        int total = HEADS * 1024 * DIM;
        pool_kernel<<<(total + 255) / 256, 256, 0, stream>>>(k, v, k1, v1, 8, 1024);
    }
    {
        int total = HEADS * 128 * DIM;
        pool_kernel<<<(total + 255) / 256, 256, 0, stream>>>(k, v, k2, v2, 64, 128);
    }
    {
        int total = HEADS * 16 * DIM;
        pool_kernel<<<(total + 255) / 256, 256, 0, stream>>>(k, v, k3, v3, 512, 16);
    }

    // attention: one 64-lane wave per 64 queries per head
    int nblocks = HEADS * (N_TOK / 64);
    attn_kernel<<<nblocks, 64, 0, stream>>>(q, k, v, gam, k1, v1, k2, v2, k3, v3, out);
}

// Round 2
// 441.804 us; speedup vs baseline: 6.1519x; 6.1519x over previous
//
#include <hip/hip_runtime.h>

#define NTOK 8192
#define NH 16
#define DD 64
#define NEGF -1e30f

typedef __attribute__((ext_vector_type(8))) short bf16x8;
typedef __attribute__((ext_vector_type(4))) float f32x4;

#define MFMA(a, b, c) __builtin_amdgcn_mfma_f32_16x16x32_bf16((a), (b), (c), 0, 0, 0)

static __device__ __forceinline__ unsigned short f2bf(float x) {
    union { float f; unsigned u; } c; c.f = x;
    unsigned r = (c.u + 0x7FFFu + ((c.u >> 16) & 1u)) >> 16;
    return (unsigned short)r;
}

// ---------------- fp32 -> bf16 row-major convert ----------------
__global__ __launch_bounds__(256) void cvt_bf16(const float* __restrict__ s,
                                                unsigned short* __restrict__ d, int n8) {
    int t = blockIdx.x * blockDim.x + threadIdx.x;
    if (t >= n8) return;
    const float4* s4 = (const float4*)s;
    float4 a = s4[2 * (size_t)t], b = s4[2 * (size_t)t + 1];
    union { unsigned short u[8]; uint4 q; } o;
    o.u[0] = f2bf(a.x); o.u[1] = f2bf(a.y); o.u[2] = f2bf(a.z); o.u[3] = f2bf(a.w);
    o.u[4] = f2bf(b.x); o.u[5] = f2bf(b.y); o.u[6] = f2bf(b.z); o.u[7] = f2bf(b.w);
    *(uint4*)(d + 8 * (size_t)t) = o.q;
}

// ---------------- v (h,n,d) fp32 -> vt (h,d,n) bf16 ----------------
__global__ __launch_bounds__(256) void transpose_v(const float* __restrict__ v,
                                                   unsigned short* __restrict__ vt) {
    int h = blockIdx.x >> 7;
    int n0 = (blockIdx.x & 127) << 6;
    __shared__ unsigned short t[64][65];
    int tid = threadIdx.x;
    int col = tid & 63;      // d
    int rr = tid >> 6;       // 0..3
    const float* src = v + ((size_t)(h * NTOK + n0)) * DD;
#pragma unroll
    for (int r = 0; r < 16; ++r) {
        int row = rr + r * 4;   // n local
        t[col][row] = f2bf(src[(size_t)row * DD + col]);
    }
    __syncthreads();
    int d = tid >> 2, ch = tid & 3;
    union { unsigned short u[16]; uint4 q[2]; } tmp;
#pragma unroll
    for (int j = 0; j < 16; ++j) tmp.u[j] = t[d][ch * 16 + j];
    unsigned short* dst = vt + ((size_t)(h * DD + d)) * NTOK + n0 + ch * 16;
    ((uint4*)dst)[0] = tmp.q[0];
    ((uint4*)dst)[1] = tmp.q[1];
}

// ---------------- pooled levels: mean over S tokens -> Kl (h,c,d) bf16, Vtl (h,d,c) bf16 ----------------
__global__ __launch_bounds__(256) void pool_lvl(const float* __restrict__ k, const float* __restrict__ v,
                                                unsigned short* __restrict__ kl,
                                                unsigned short* __restrict__ vtl,
                                                int S, int Creal, int Cpad) {
    int tid = blockIdx.x * blockDim.x + threadIdx.x;
    int total = NH * Cpad * DD;
    if (tid >= total) return;
    int d = tid & 63;
    int cc = (tid >> 6) % Cpad;
    int h = tid / (DD * Cpad);
    float km = 0.f, vm = 0.f;
    if (cc < Creal) {
        size_t base = ((size_t)(h * NTOK + cc * S)) * DD + d;
        for (int r = 0; r < S; ++r) {
            km += k[base + (size_t)r * DD];
            vm += v[base + (size_t)r * DD];
        }
        float inv = 1.0f / (float)S;
        km *= inv; vm *= inv;
    }
    kl[((size_t)(h * Cpad + cc)) * DD + d] = f2bf(km);
    vtl[((size_t)(h * DD + d)) * Cpad + cc] = f2bf(vm);
}

// ---------------- main attention ----------------
// 4 waves/block, each wave owns 16 queries. Swapped QK^T (S^T = K*Q^T) with
// key-permuted tiles so P^T lands directly in PV B-frag layout.
__global__ __launch_bounds__(256, 4) void attn_mfma(
    const unsigned short* __restrict__ Qb, const unsigned short* __restrict__ Kb,
    const unsigned short* __restrict__ Vtb,
    const unsigned short* __restrict__ K1, const unsigned short* __restrict__ Vt1,
    const unsigned short* __restrict__ K2, const unsigned short* __restrict__ Vt2,
    const unsigned short* __restrict__ K3, const unsigned short* __restrict__ Vt3,
    const float* __restrict__ gam, float* __restrict__ out) {
    const int lane = threadIdx.x & 63;
    const int wid = threadIdx.x >> 6;
    const int h = blockIdx.x >> 7;
    const int Qs = ((blockIdx.x & 127) << 6) + wid * 16;
    const int g = lane >> 4;        // lane group 0..3
    const int c = lane & 15;        // query column / tile-row selector
    const int i_q = Qs + c;
    const float scale = 0.125f;

    const float g0 = gam[0], g1 = gam[1], g2 = gam[2], g3 = gam[3];

    // Q fragments (B-operand of S^T mfma): row c, 8 contiguous bf16 at d = g*8 (+32)
    const unsigned short* Qrow = Qb + ((size_t)(h * NTOK + Qs + c)) * DD;
    bf16x8 q0 = *(const bf16x8*)(const void*)(Qrow + g * 8);
    bf16x8 q1 = *(const bf16x8*)(const void*)(Qrow + 32 + g * 8);

    f32x4 oacc[4];
#pragma unroll
    for (int t = 0; t < 4; ++t) oacc[t] = (f32x4){0.f, 0.f, 0.f, 0.f};
    float m = NEGF, l = 0.f;

    // process 32 keys (two 16-key S^T tiles with permuted key->row mapping)
    auto proc = [&](const unsigned short* kb, const unsigned short* vtb, int ldn,
                    int key0, int S, float gamma, bool lvl0) {
        // tile row c maps to physical key: tileA -> key0 + 8*(c>>2) + (c&3); tileB -> +4
        int pk = key0 + 8 * (c >> 2) + (c & 3);
        const unsigned short* kra = kb + (size_t)pk * DD + g * 8;
        const unsigned short* krb = kra + 4 * DD;
        bf16x8 ka0 = *(const bf16x8*)(const void*)(kra);
        bf16x8 ka1 = *(const bf16x8*)(const void*)(kra + 32);
        bf16x8 kb0 = *(const bf16x8*)(const void*)(krb);
        bf16x8 kb1 = *(const bf16x8*)(const void*)(krb + 32);
        f32x4 z = {0.f, 0.f, 0.f, 0.f};
        f32x4 sA = MFMA(ka1, q1, MFMA(ka0, q0, z));
        f32x4 sB = MFMA(kb1, q1, MFMA(kb0, q0, z));

        // lane holds D rows 4g+r: tileA -> key0+8g+r, tileB -> key0+8g+4+r
        float sv[8];
#pragma unroll
        for (int r = 0; r < 4; ++r) {
            int keyA = key0 + 8 * g + r;
            int keyB = keyA + 4;
            int ja = lvl0 ? keyA : (keyA * S + S - 1);
            int jb = lvl0 ? keyB : (keyB * S + S - 1);
            int da = i_q - ja, db = i_q - jb;
            bool aA = lvl0 ? ((unsigned)da <= 127u) : (da >= 128);
            bool aB = lvl0 ? ((unsigned)db <= 127u) : (db >= 128);
            sv[r]     = aA ? sA[r] * scale - gamma * (float)da : NEGF;
            sv[4 + r] = aB ? sB[r] * scale - gamma * (float)db : NEGF;
        }
        float tm = sv[0];
#pragma unroll
        for (int r = 1; r < 8; ++r) tm = fmaxf(tm, sv[r]);
        tm = fmaxf(tm, __shfl_xor(tm, 16));
        tm = fmaxf(tm, __shfl_xor(tm, 32));
        if (__any(tm > m)) {
            float mn = fmaxf(m, tm);
            float sf = __expf(m - mn);
            m = mn;
            l *= sf;
#pragma unroll
            for (int t = 0; t < 4; ++t) oacc[t] *= sf;
        }
        float ps = 0.f;
        union { unsigned short u[8]; bf16x8 v; } pf;
#pragma unroll
        for (int r = 0; r < 8; ++r) {
            float p = __expf(sv[r] - m);
            ps += p;
            pf.u[r] = f2bf(p);
        }
        ps += __shfl_xor(ps, 16);
        ps += __shfl_xor(ps, 32);
        l += ps;
        // PV: O^T += V^T * P^T ; A-frag = 8 contiguous keys from Vt row (d = db*16 + c)
        const unsigned short* vr = vtb + (size_t)c * ldn + key0 + g * 8;
#pragma unroll
        for (int db = 0; db < 4; ++db) {
            bf16x8 vf = *(const bf16x8*)(const void*)(vr + (size_t)db * 16 * ldn);
            oacc[db] = MFMA(vf, pf.v, oacc[db]);
        }
    };

    // ---- level 0: sliding window, newest tiles first ----
    {
        const unsigned short* KbH = Kb + (size_t)h * NTOK * DD;
        const unsigned short* VtH = Vtb + (size_t)h * DD * NTOK;
        int lo = Qs - 127; if (lo < 0) lo = 0; lo &= ~31;
        for (int key0 = (Qs + 15) & ~31; key0 >= lo; key0 -= 32)
            proc(KbH, VtH, NTOK, key0, 1, g0, true);
    }
    // ---- hierarchical levels, newest chunks first ----
    {
        const int S = 8, Cpad = 1024;
        int cm = Qs + 15 - 127 - S;
        if (cm >= 0) {
            cm /= S;
            const unsigned short* KH = K1 + (size_t)h * Cpad * DD;
            const unsigned short* VH = Vt1 + (size_t)h * DD * Cpad;
            for (int c0 = cm & ~31; c0 >= 0; c0 -= 32) proc(KH, VH, Cpad, c0, S, g1, false);
        }
    }
    {
        const int S = 64, Cpad = 128;
        int cm = Qs + 15 - 127 - S;
        if (cm >= 0) {
            cm /= S;
            const unsigned short* KH = K2 + (size_t)h * Cpad * DD;
            const unsigned short* VH = Vt2 + (size_t)h * DD * Cpad;
            for (int c0 = cm & ~31; c0 >= 0; c0 -= 32) proc(KH, VH, Cpad, c0, S, g2, false);
        }
    }
    {
        const int S = 512, Cpad = 32;
        int cm = Qs + 15 - 127 - S;
        if (cm >= 0) {
            cm /= S;
            const unsigned short* KH = K3 + (size_t)h * Cpad * DD;
            const unsigned short* VH = Vt3 + (size_t)h * DD * Cpad;
            for (int c0 = cm & ~31; c0 >= 0; c0 -= 32) proc(KH, VH, Cpad, c0, S, g3, false);
        }
    }

    // ---- write out: lane holds O[q=c][d = db*16 + 4g + r] ----
    float invl = 1.0f / fmaxf(l, 1e-8f);
    float* orow = out + ((size_t)(h * NTOK + Qs + c)) * DD;
#pragma unroll
    for (int db = 0; db < 4; ++db) {
        float4 x;
        x.x = oacc[db][0] * invl;
        x.y = oacc[db][1] * invl;
        x.z = oacc[db][2] * invl;
        x.w = oacc[db][3] * invl;
        *(float4*)(orow + db * 16 + 4 * g) = x;
    }
}

extern "C" void kernel_launch(void* const* d_in, const int* in_sizes, int n_in,
                              void* d_out, int out_size, void* d_ws, size_t ws_size,
                              hipStream_t stream) {
    const float* q = (const float*)d_in[0];
    const float* k = (const float*)d_in[1];
    const float* v = (const float*)d_in[2];
    const float* gam = (const float*)d_in[3];
    float* out = (float*)d_out;

    char* w = (char*)d_ws;
    const size_t bigN = (size_t)NH * NTOK * DD * sizeof(unsigned short);  // 16.78 MB
    unsigned short* Qb = (unsigned short*)w;            w += bigN;
    unsigned short* Kb = (unsigned short*)w;            w += bigN;
    unsigned short* Vtb = (unsigned short*)w;           w += bigN;
    unsigned short* K1 = (unsigned short*)w;            w += (size_t)NH * 1024 * DD * 2;
    unsigned short* Vt1 = (unsigned short*)w;           w += (size_t)NH * 1024 * DD * 2;
    unsigned short* K2 = (unsigned short*)w;            w += (size_t)NH * 128 * DD * 2;
    unsigned short* Vt2 = (unsigned short*)w;           w += (size_t)NH * 128 * DD * 2;
    unsigned short* K3 = (unsigned short*)w;            w += (size_t)NH * 32 * DD * 2;
    unsigned short* Vt3 = (unsigned short*)w;           w += (size_t)NH * 32 * DD * 2;

    int n8 = NH * NTOK * DD / 8;
    cvt_bf16<<<n8 / 256, 256, 0, stream>>>(q, Qb, n8);
    cvt_bf16<<<n8 / 256, 256, 0, stream>>>(k, Kb, n8);
    transpose_v<<<NH * (NTOK / 64), 256, 0, stream>>>(v, Vtb);
    pool_lvl<<<NH * 1024 * DD / 256, 256, 0, stream>>>(k, v, K1, Vt1, 8, 1024, 1024);
    pool_lvl<<<NH * 128 * DD / 256, 256, 0, stream>>>(k, v, K2, Vt2, 64, 128, 128);
    pool_lvl<<<NH * 32 * DD / 256, 256, 0, stream>>>(k, v, K3, Vt3, 512, 16, 32);

    attn_mfma<<<NH * (NTOK / 64), 256, 0, stream>>>(Qb, Kb, Vtb, K1, Vt1, K2, Vt2, K3, Vt3, gam, out);
}

// Round 3
// 240.448 us; speedup vs baseline: 11.3037x; 1.8374x over previous
//
#include <hip/hip_runtime.h>

#define NTOK 8192
#define NH 16
#define DD 64
#define NEGF -1e30f
#define LOG2E 1.4426950408889634f

typedef __attribute__((ext_vector_type(8))) short bf16x8;
typedef __attribute__((ext_vector_type(4))) float f32x4;

#define MFMA(a, b, c) __builtin_amdgcn_mfma_f32_16x16x32_bf16((a), (b), (c), 0, 0, 0)

static __device__ __forceinline__ unsigned short f2bf(float x) {
    union { float f; unsigned u; } c; c.f = x;
    unsigned r = (c.u + 0x7FFFu + ((c.u >> 16) & 1u)) >> 16;
    return (unsigned short)r;
}
static __device__ __forceinline__ float bf2f(unsigned short x) {
    union { unsigned u; float f; } c; c.u = ((unsigned)x) << 16;
    return c.f;
}

// ---------------- fp32 -> bf16 row-major convert (optional scale) ----------------
__global__ __launch_bounds__(256) void cvt_bf16(const float* __restrict__ s,
                                                unsigned short* __restrict__ d,
                                                float scale, int n8) {
    int t = blockIdx.x * blockDim.x + threadIdx.x;
    if (t >= n8) return;
    const float4* s4 = (const float4*)s;
    float4 a = s4[2 * (size_t)t], b = s4[2 * (size_t)t + 1];
    union { unsigned short u[8]; uint4 q; } o;
    o.u[0] = f2bf(a.x * scale); o.u[1] = f2bf(a.y * scale);
    o.u[2] = f2bf(a.z * scale); o.u[3] = f2bf(a.w * scale);
    o.u[4] = f2bf(b.x * scale); o.u[5] = f2bf(b.y * scale);
    o.u[6] = f2bf(b.z * scale); o.u[7] = f2bf(b.w * scale);
    *(uint4*)(d + 8 * (size_t)t) = o.q;
}

// ---------------- v (h,n,d) fp32 -> vt (h,d,n) bf16 ----------------
__global__ __launch_bounds__(256) void transpose_v(const float* __restrict__ v,
                                                   unsigned short* __restrict__ vt) {
    int h = blockIdx.x >> 7;
    int n0 = (blockIdx.x & 127) << 6;
    __shared__ unsigned short t[64][65];
    int tid = threadIdx.x;
    int col = tid & 63;      // d
    int rr = tid >> 6;       // 0..3
    const float* src = v + ((size_t)(h * NTOK + n0)) * DD;
#pragma unroll
    for (int r = 0; r < 16; ++r) {
        int row = rr + r * 4;   // n local
        t[col][row] = f2bf(src[(size_t)row * DD + col]);
    }
    __syncthreads();
    int d = tid >> 2, ch = tid & 3;
    union { unsigned short u[16]; uint4 q[2]; } tmp;
#pragma unroll
    for (int j = 0; j < 16; ++j) tmp.u[j] = t[d][ch * 16 + j];
    unsigned short* dst = vt + ((size_t)(h * DD + d)) * NTOK + n0 + ch * 16;
    ((uint4*)dst)[0] = tmp.q[0];
    ((uint4*)dst)[1] = tmp.q[1];
}

// ---------------- level-1 pool: mean over 8 raw tokens -> K1 (h,c,d), Vt1 (h,d,c) ----------------
__global__ __launch_bounds__(256) void pool1_kernel(const float* __restrict__ k, const float* __restrict__ v,
                                                    unsigned short* __restrict__ k1,
                                                    unsigned short* __restrict__ vt1) {
    int tid = blockIdx.x * blockDim.x + threadIdx.x;   // NH*1024*64
    int d = tid & 63;
    int c = (tid >> 6) & 1023;
    int h = tid >> 16;
    size_t base = ((size_t)(h * NTOK + c * 8)) * DD + d;
    float ks = 0.f, vs = 0.f;
#pragma unroll
    for (int r = 0; r < 8; ++r) {
        ks += k[base + (size_t)r * DD];
        vs += v[base + (size_t)r * DD];
    }
    ks *= 0.125f; vs *= 0.125f;
    k1[((size_t)(h * 1024 + c)) * DD + d] = f2bf(ks);
    vt1[((size_t)(h * DD + d)) * 1024 + c] = f2bf(vs);
}

// ---------------- level-2 pool: mean over 8 level-1 chunks ----------------
__global__ __launch_bounds__(256) void pool2_kernel(const unsigned short* __restrict__ k1,
                                                    const unsigned short* __restrict__ vt1,
                                                    unsigned short* __restrict__ k2,
                                                    unsigned short* __restrict__ vt2) {
    int tid = blockIdx.x * blockDim.x + threadIdx.x;   // NH*128*64
    int d = tid & 63;
    int c = (tid >> 6) & 127;
    int h = tid >> 13;
    float ks = 0.f, vs = 0.f;
#pragma unroll
    for (int j = 0; j < 8; ++j) {
        ks += bf2f(k1[((size_t)(h * 1024 + c * 8 + j)) * DD + d]);
        vs += bf2f(vt1[((size_t)(h * DD + d)) * 1024 + c * 8 + j]);
    }
    k2[((size_t)(h * 128 + c)) * DD + d] = f2bf(ks * 0.125f);
    vt2[((size_t)(h * DD + d)) * 128 + c] = f2bf(vs * 0.125f);
}

// ---------------- level-3 pool: mean over 8 level-2 chunks, padded to 32 ----------------
__global__ __launch_bounds__(256) void pool3_kernel(const unsigned short* __restrict__ k2,
                                                    const unsigned short* __restrict__ vt2,
                                                    unsigned short* __restrict__ k3,
                                                    unsigned short* __restrict__ vt3) {
    int tid = blockIdx.x * blockDim.x + threadIdx.x;   // NH*32*64
    int d = tid & 63;
    int c = (tid >> 6) & 31;
    int h = tid >> 11;
    float ks = 0.f, vs = 0.f;
    if (c < 16) {
#pragma unroll
        for (int j = 0; j < 8; ++j) {
            ks += bf2f(k2[((size_t)(h * 128 + c * 8 + j)) * DD + d]);
            vs += bf2f(vt2[((size_t)(h * DD + d)) * 128 + c * 8 + j]);
        }
        ks *= 0.125f; vs *= 0.125f;
    }
    k3[((size_t)(h * 32 + c)) * DD + d] = f2bf(ks);
    vt3[((size_t)(h * DD + d)) * 32 + c] = f2bf(vs);
}

// ---------------- per-level inner loop ----------------
// Swapped QK^T with key-permuted tiles; exp2 domain; fast path for fully-visible groups.
template<int S, int LDN, bool L0>
__device__ __forceinline__ void do_level(
    const unsigned short* __restrict__ Kh, const unsigned short* __restrict__ Vth,
    int c0_top, int c0_lo, int Qs, float gp, int i_q, int g, int c,
    bf16x8 q0, bf16x8 q1, float& m, float& l, f32x4* oacc) {

    const float gps = gp * (float)S;
    const float fb = gp * (float)i_q - gps * (float)(8 * g) - gp * (float)(S - 1);
    float c0f = (float)c0_top;
    int c_all = -1;
    if (!L0) {
        int num = Qs - 128 - (S - 1);
        if (num >= 0) c_all = num / S;
    }
    const unsigned short* kb = Kh + ((size_t)(c0_top + 8 * (c >> 2) + (c & 3))) * DD + g * 8;
    const unsigned short* vb = Vth + (size_t)c * LDN + c0_top + g * 8;

    for (int c0 = c0_top; c0 >= c0_lo; c0 -= 32, c0f -= 32.f, kb -= 32 * DD, vb -= 32) {
        bf16x8 ka0 = *(const bf16x8*)(const void*)(kb);
        bf16x8 ka1 = *(const bf16x8*)(const void*)(kb + 32);
        bf16x8 kb0 = *(const bf16x8*)(const void*)(kb + 4 * DD);
        bf16x8 kb1 = *(const bf16x8*)(const void*)(kb + 4 * DD + 32);
        bf16x8 vf0 = *(const bf16x8*)(const void*)(vb);
        bf16x8 vf1 = *(const bf16x8*)(const void*)(vb + 16 * LDN);
        bf16x8 vf2 = *(const bf16x8*)(const void*)(vb + 32 * LDN);
        bf16x8 vf3 = *(const bf16x8*)(const void*)(vb + 48 * LDN);

        f32x4 z = {0.f, 0.f, 0.f, 0.f};
        f32x4 sA = MFMA(ka1, q1, MFMA(ka0, q0, z));
        f32x4 sB = MFMA(kb1, q1, MFMA(kb0, q0, z));

        float sv[8];
        bool fast = L0 ? ((c0 >= Qs - 112) && (c0 + 31 <= Qs)) : (c0 + 31 <= c_all);
        if (fast) {
            float u = fmaf(gps, c0f, -fb);
            sv[0] = sA[0] + u; u += gps;
            sv[1] = sA[1] + u; u += gps;
            sv[2] = sA[2] + u; u += gps;
            sv[3] = sA[3] + u; u += gps;
            sv[4] = sB[0] + u; u += gps;
            sv[5] = sB[1] + u; u += gps;
            sv[6] = sB[2] + u; u += gps;
            sv[7] = sB[3] + u;
        } else {
#pragma unroll
            for (int r = 0; r < 4; ++r) {
                int cA = c0 + 8 * g + r, cB = cA + 4;
                int jA = L0 ? cA : (cA * S + S - 1);
                int jB = L0 ? cB : (cB * S + S - 1);
                int dA = i_q - jA, dB = i_q - jB;
                bool aA = L0 ? ((unsigned)dA <= 127u) : (dA >= 128);
                bool aB = L0 ? ((unsigned)dB <= 127u) : (dB >= 128);
                sv[r]     = aA ? fmaf(-gp, (float)dA, sA[r]) : NEGF;
                sv[r + 4] = aB ? fmaf(-gp, (float)dB, sB[r]) : NEGF;
            }
        }

        float tm = fmaxf(fmaxf(fmaxf(sv[0], sv[1]), fmaxf(sv[2], sv[3])),
                         fmaxf(fmaxf(sv[4], sv[5]), fmaxf(sv[6], sv[7])));
        tm = fmaxf(tm, __shfl_xor(tm, 16));
        tm = fmaxf(tm, __shfl_xor(tm, 32));
        if (__any(tm > m + 8.f)) {          // defer-max: skip rescale for small growth
            float mn = fmaxf(m, tm);
            float sf = exp2f(m - mn);
            m = mn;
            l *= sf;
#pragma unroll
            for (int t2 = 0; t2 < 4; ++t2) oacc[t2] *= sf;
        }
        float p[8];
#pragma unroll
        for (int r = 0; r < 8; ++r) p[r] = exp2f(sv[r] - m);
        l += ((p[0] + p[1]) + (p[2] + p[3])) + ((p[4] + p[5]) + (p[6] + p[7]));

        union { unsigned u32[4]; bf16x8 v8; } pf;
#pragma unroll
        for (int j = 0; j < 4; ++j)
            asm("v_cvt_pk_bf16_f32 %0, %1, %2" : "=v"(pf.u32[j]) : "v"(p[2 * j]), "v"(p[2 * j + 1]));

        oacc[0] = MFMA(vf0, pf.v8, oacc[0]);
        oacc[1] = MFMA(vf1, pf.v8, oacc[1]);
        oacc[2] = MFMA(vf2, pf.v8, oacc[2]);
        oacc[3] = MFMA(vf3, pf.v8, oacc[3]);
    }
}

// ---------------- main attention ----------------
__global__ __launch_bounds__(256, 4) void attn_mfma(
    const unsigned short* __restrict__ Qb, const unsigned short* __restrict__ Kb,
    const unsigned short* __restrict__ Vtb,
    const unsigned short* __restrict__ K1, const unsigned short* __restrict__ Vt1,
    const unsigned short* __restrict__ K2, const unsigned short* __restrict__ Vt2,
    const unsigned short* __restrict__ K3, const unsigned short* __restrict__ Vt3,
    const float* __restrict__ gam, float* __restrict__ out) {
    const int lane = threadIdx.x & 63;
    const int wid = threadIdx.x >> 6;
    // balance remap: h = low bits (same head per CU, 2 heads per XCD);
    // q-tile = high bits (stride-256 CU revisit spans the q range uniformly)
    const int h = blockIdx.x & 15;
    const int qt = blockIdx.x >> 4;
    const int Qs = (qt << 6) + wid * 16;
    const int g = lane >> 4;
    const int c = lane & 15;
    const int i_q = Qs + c;

    const float g0 = gam[0] * LOG2E, g1 = gam[1] * LOG2E;
    const float g2 = gam[2] * LOG2E, g3 = gam[3] * LOG2E;

    const unsigned short* Qrow = Qb + ((size_t)(h * NTOK + i_q)) * DD;
    bf16x8 q0 = *(const bf16x8*)(const void*)(Qrow + g * 8);
    bf16x8 q1 = *(const bf16x8*)(const void*)(Qrow + 32 + g * 8);

    f32x4 oacc[4];
#pragma unroll
    for (int t = 0; t < 4; ++t) oacc[t] = (f32x4){0.f, 0.f, 0.f, 0.f};
    float m = NEGF, l = 0.f;

    // level 0 (newest first; first group always has active keys per query)
    {
        int lo = Qs - 127; if (lo < 0) lo = 0; lo &= ~31;
        int top = (Qs + 15) & ~31;
        do_level<1, NTOK, true>(Kb + (size_t)h * NTOK * DD, Vtb + (size_t)h * DD * NTOK,
                                top, lo, Qs, g0, i_q, g, c, q0, q1, m, l, oacc);
    }
    {
        int cm = Qs - 120;                 // Qs+15-127-8
        if (cm >= 0)
            do_level<8, 1024, false>(K1 + (size_t)h * 1024 * DD, Vt1 + (size_t)h * DD * 1024,
                                     (cm / 8) & ~31, 0, Qs, g1, i_q, g, c, q0, q1, m, l, oacc);
    }
    {
        int cm = Qs - 176;                 // Qs+15-127-64
        if (cm >= 0)
            do_level<64, 128, false>(K2 + (size_t)h * 128 * DD, Vt2 + (size_t)h * DD * 128,
                                     (cm / 64) & ~31, 0, Qs, g2, i_q, g, c, q0, q1, m, l, oacc);
    }
    {
        int cm = Qs - 624;                 // Qs+15-127-512
        if (cm >= 0)
            do_level<512, 32, false>(K3 + (size_t)h * 32 * DD, Vt3 + (size_t)h * DD * 32,
                                     (cm / 512) & ~31, 0, Qs, g3, i_q, g, c, q0, q1, m, l, oacc);
    }

    // final l reduce over the 4 g-lanes of each query column
    float lt = l + __shfl_xor(l, 16);
    lt += __shfl_xor(lt, 32);
    float invl = 1.0f / fmaxf(lt, 1e-8f);

    float* orow = out + ((size_t)(h * NTOK + i_q)) * DD;
#pragma unroll
    for (int db = 0; db < 4; ++db) {
        float4 x;
        x.x = oacc[db][0] * invl;
        x.y = oacc[db][1] * invl;
        x.z = oacc[db][2] * invl;
        x.w = oacc[db][3] * invl;
        *(float4*)(orow + db * 16 + 4 * g) = x;
    }
}

extern "C" void kernel_launch(void* const* d_in, const int* in_sizes, int n_in,
                              void* d_out, int out_size, void* d_ws, size_t ws_size,
                              hipStream_t stream) {
    const float* q = (const float*)d_in[0];
    const float* k = (const float*)d_in[1];
    const float* v = (const float*)d_in[2];
    const float* gam = (const float*)d_in[3];
    float* out = (float*)d_out;

    char* w = (char*)d_ws;
    const size_t bigN = (size_t)NH * NTOK * DD * sizeof(unsigned short);
    unsigned short* Qb = (unsigned short*)w;            w += bigN;
    unsigned short* Kb = (unsigned short*)w;            w += bigN;
    unsigned short* Vtb = (unsigned short*)w;           w += bigN;
    unsigned short* K1 = (unsigned short*)w;            w += (size_t)NH * 1024 * DD * 2;
    unsigned short* Vt1 = (unsigned short*)w;           w += (size_t)NH * 1024 * DD * 2;
    unsigned short* K2 = (unsigned short*)w;            w += (size_t)NH * 128 * DD * 2;
    unsigned short* Vt2 = (unsigned short*)w;           w += (size_t)NH * 128 * DD * 2;
    unsigned short* K3 = (unsigned short*)w;            w += (size_t)NH * 32 * DD * 2;
    unsigned short* Vt3 = (unsigned short*)w;           w += (size_t)NH * 32 * DD * 2;

    int n8 = NH * NTOK * DD / 8;
    const float qscale = 0.125f * LOG2E;   // fold softmax scale + log2e into Q
    cvt_bf16<<<n8 / 256, 256, 0, stream>>>(q, Qb, qscale, n8);
    cvt_bf16<<<n8 / 256, 256, 0, stream>>>(k, Kb, 1.0f, n8);
    transpose_v<<<NH * (NTOK / 64), 256, 0, stream>>>(v, Vtb);
    pool1_kernel<<<NH * 1024 * DD / 256, 256, 0, stream>>>(k, v, K1, Vt1);
    pool2_kernel<<<NH * 128 * DD / 256, 256, 0, stream>>>(K1, Vt1, K2, Vt2);
    pool3_kernel<<<NH * 32 * DD / 256, 256, 0, stream>>>(K2, Vt2, K3, Vt3);

    attn_mfma<<<NH * (NTOK / 64), 256, 0, stream>>>(Qb, Kb, Vtb, K1, Vt1, K2, Vt2, K3, Vt3, gam, out);
}

// Round 4
// 240.417 us; speedup vs baseline: 11.3052x; 1.0001x over previous
//
#include <hip/hip_runtime.h>

#define NTOK 8192
#define NH 16
#define DD 64
#define NEGF -1e30f
#define LOG2E 1.4426950408889634f

typedef __attribute__((ext_vector_type(8))) short bf16x8;
typedef __attribute__((ext_vector_type(4))) float f32x4;

#define MFMA(a, b, c) __builtin_amdgcn_mfma_f32_16x16x32_bf16((a), (b), (c), 0, 0, 0)
#define EXP2(x) __builtin_amdgcn_exp2f(x)

static __device__ __forceinline__ unsigned short f2bf(float x) {
    union { float f; unsigned u; } c; c.f = x;
    unsigned r = (c.u + 0x7FFFu + ((c.u >> 16) & 1u)) >> 16;
    return (unsigned short)r;
}
static __device__ __forceinline__ float bf2f(unsigned short x) {
    union { unsigned u; float f; } c; c.u = ((unsigned)x) << 16;
    return c.f;
}

// ---------------- fp32 -> bf16 row-major convert (optional scale) ----------------
__global__ __launch_bounds__(256) void cvt_bf16(const float* __restrict__ s,
                                                unsigned short* __restrict__ d,
                                                float scale, int n8) {
    int t = blockIdx.x * blockDim.x + threadIdx.x;
    if (t >= n8) return;
    const float4* s4 = (const float4*)s;
    float4 a = s4[2 * (size_t)t], b = s4[2 * (size_t)t + 1];
    union { unsigned short u[8]; uint4 q; } o;
    o.u[0] = f2bf(a.x * scale); o.u[1] = f2bf(a.y * scale);
    o.u[2] = f2bf(a.z * scale); o.u[3] = f2bf(a.w * scale);
    o.u[4] = f2bf(b.x * scale); o.u[5] = f2bf(b.y * scale);
    o.u[6] = f2bf(b.z * scale); o.u[7] = f2bf(b.w * scale);
    *(uint4*)(d + 8 * (size_t)t) = o.q;
}

// ---------------- v (h,n,d) fp32 -> vt (h,d,n) bf16 ----------------
__global__ __launch_bounds__(256) void transpose_v(const float* __restrict__ v,
                                                   unsigned short* __restrict__ vt) {
    int h = blockIdx.x >> 7;
    int n0 = (blockIdx.x & 127) << 6;
    __shared__ unsigned short t[64][65];
    int tid = threadIdx.x;
    int col = tid & 63;      // d
    int rr = tid >> 6;       // 0..3
    const float* src = v + ((size_t)(h * NTOK + n0)) * DD;
#pragma unroll
    for (int r = 0; r < 16; ++r) {
        int row = rr + r * 4;   // n local
        t[col][row] = f2bf(src[(size_t)row * DD + col]);
    }
    __syncthreads();
    int d = tid >> 2, ch = tid & 3;
    union { unsigned short u[16]; uint4 q[2]; } tmp;
#pragma unroll
    for (int j = 0; j < 16; ++j) tmp.u[j] = t[d][ch * 16 + j];
    unsigned short* dst = vt + ((size_t)(h * DD + d)) * NTOK + n0 + ch * 16;
    ((uint4*)dst)[0] = tmp.q[0];
    ((uint4*)dst)[1] = tmp.q[1];
}

// ---------------- level-1 pool: mean over 8 raw tokens -> K1 (h,c,d), Vt1 (h,d,c) ----------------
__global__ __launch_bounds__(256) void pool1_kernel(const float* __restrict__ k, const float* __restrict__ v,
                                                    unsigned short* __restrict__ k1,
                                                    unsigned short* __restrict__ vt1) {
    int tid = blockIdx.x * blockDim.x + threadIdx.x;   // NH*1024*64
    int d = tid & 63;
    int c = (tid >> 6) & 1023;
    int h = tid >> 16;
    size_t base = ((size_t)(h * NTOK + c * 8)) * DD + d;
    float ks = 0.f, vs = 0.f;
#pragma unroll
    for (int r = 0; r < 8; ++r) {
        ks += k[base + (size_t)r * DD];
        vs += v[base + (size_t)r * DD];
    }
    ks *= 0.125f; vs *= 0.125f;
    k1[((size_t)(h * 1024 + c)) * DD + d] = f2bf(ks);
    vt1[((size_t)(h * DD + d)) * 1024 + c] = f2bf(vs);
}

// ---------------- level-2 pool: mean over 8 level-1 chunks ----------------
__global__ __launch_bounds__(256) void pool2_kernel(const unsigned short* __restrict__ k1,
                                                    const unsigned short* __restrict__ vt1,
                                                    unsigned short* __restrict__ k2,
                                                    unsigned short* __restrict__ vt2) {
    int tid = blockIdx.x * blockDim.x + threadIdx.x;   // NH*128*64
    int d = tid & 63;
    int c = (tid >> 6) & 127;
    int h = tid >> 13;
    float ks = 0.f, vs = 0.f;
#pragma unroll
    for (int j = 0; j < 8; ++j) {
        ks += bf2f(k1[((size_t)(h * 1024 + c * 8 + j)) * DD + d]);
        vs += bf2f(vt1[((size_t)(h * DD + d)) * 1024 + c * 8 + j]);
    }
    k2[((size_t)(h * 128 + c)) * DD + d] = f2bf(ks * 0.125f);
    vt2[((size_t)(h * DD + d)) * 128 + c] = f2bf(vs * 0.125f);
}

// ---------------- level-3 pool: mean over 8 level-2 chunks, padded to 32 ----------------
__global__ __launch_bounds__(256) void pool3_kernel(const unsigned short* __restrict__ k2,
                                                    const unsigned short* __restrict__ vt2,
                                                    unsigned short* __restrict__ k3,
                                                    unsigned short* __restrict__ vt3) {
    int tid = blockIdx.x * blockDim.x + threadIdx.x;   // NH*32*64
    int d = tid & 63;
    int c = (tid >> 6) & 31;
    int h = tid >> 11;
    float ks = 0.f, vs = 0.f;
    if (c < 16) {
#pragma unroll
        for (int j = 0; j < 8; ++j) {
            ks += bf2f(k2[((size_t)(h * 128 + c * 8 + j)) * DD + d]);
            vs += bf2f(vt2[((size_t)(h * DD + d)) * 128 + c * 8 + j]);
        }
        ks *= 0.125f; vs *= 0.125f;
    }
    k3[((size_t)(h * 32 + c)) * DD + d] = f2bf(ks);
    vt3[((size_t)(h * DD + d)) * 32 + c] = f2bf(vs);
}

// K fragments of one 32-key group (2 permuted 16-key tiles)
struct KG { bf16x8 k0, k1, k2, k3; };

// ---------------- per-level inner loop ----------------
// Swapped QK^T, key-permuted tiles, exp2 domain, wave-uniform deferred max
// (no cross-lane shuffle in steady state), K register-prefetch, early V issue.
template<int S, int LDN, bool L0>
__device__ __forceinline__ void do_level(
    const unsigned short* __restrict__ Kh, const unsigned short* __restrict__ Vth,
    int c0_top, int c0_lo, int Qs, float gp, int i_q, int g, int c,
    bf16x8 q0, bf16x8 q1, float& m, float& l, f32x4* oacc) {

    const float gps = gp * (float)S;
    const float negfb = gps * (float)(8 * g) + gp * (float)(S - 1) - gp * (float)i_q;
    int c_all = -1;
    if (!L0) {
        int num = Qs - 128 - (S - 1);
        if (num >= 0) c_all = num / S;
    }
    const unsigned short* kb = Kh + ((size_t)(8 * (c >> 2) + (c & 3))) * DD + g * 8;
    const unsigned short* vb = Vth + (size_t)c * LDN + g * 8;

    auto LOADK = [&](int c0) -> KG {
        KG r;
        const unsigned short* ka = kb + (size_t)c0 * DD;
        r.k0 = *(const bf16x8*)(const void*)(ka);
        r.k1 = *(const bf16x8*)(const void*)(ka + 32);
        r.k2 = *(const bf16x8*)(const void*)(ka + 4 * DD);
        r.k3 = *(const bf16x8*)(const void*)(ka + 4 * DD + 32);
        return r;
    };

    auto COMPUTE = [&](const KG& t, int c0, float c0f) {
        // issue V loads first: their latency hides under QK^T + softmax
        const unsigned short* va = vb + c0;
        bf16x8 vf0 = *(const bf16x8*)(const void*)(va);
        bf16x8 vf1 = *(const bf16x8*)(const void*)(va + 16 * LDN);
        bf16x8 vf2 = *(const bf16x8*)(const void*)(va + 32 * LDN);
        bf16x8 vf3 = *(const bf16x8*)(const void*)(va + 48 * LDN);

        f32x4 z = {0.f, 0.f, 0.f, 0.f};
        f32x4 sA = MFMA(t.k1, q1, MFMA(t.k0, q0, z));
        f32x4 sB = MFMA(t.k3, q1, MFMA(t.k2, q0, z));

        float sv[8];
        bool fast = L0 ? ((c0 >= Qs - 112) && (c0 + 31 <= Qs)) : (c0 + 31 <= c_all);
        if (fast) {
            float u0 = fmaf(gps, c0f, negfb);
            sv[0] = sA[0] + u0;
            sv[1] = sA[1] + fmaf(gps, 1.f, u0);
            sv[2] = sA[2] + fmaf(gps, 2.f, u0);
            sv[3] = sA[3] + fmaf(gps, 3.f, u0);
            sv[4] = sB[0] + fmaf(gps, 4.f, u0);
            sv[5] = sB[1] + fmaf(gps, 5.f, u0);
            sv[6] = sB[2] + fmaf(gps, 6.f, u0);
            sv[7] = sB[3] + fmaf(gps, 7.f, u0);
        } else {
#pragma unroll
            for (int r = 0; r < 4; ++r) {
                int cA = c0 + 8 * g + r, cB = cA + 4;
                int jA = L0 ? cA : (cA * S + S - 1);
                int jB = L0 ? cB : (cB * S + S - 1);
                int dA = i_q - jA, dB = i_q - jB;
                bool aA = L0 ? ((unsigned)dA <= 127u) : (dA >= 128);
                bool aB = L0 ? ((unsigned)dB <= 127u) : (dB >= 128);
                sv[r]     = aA ? fmaf(-gp, (float)dA, sA[r]) : NEGF;
                sv[r + 4] = aB ? fmaf(-gp, (float)dB, sB[r]) : NEGF;
            }
        }

        // per-lane max only; m is wave-uniform so no per-group shuffle needed
        float tm = fmaxf(fmaxf(fmaxf(sv[0], sv[1]), fmaxf(sv[2], sv[3])),
                         fmaxf(fmaxf(sv[4], sv[5]), fmaxf(sv[6], sv[7])));
        if (__any(tm > m + 8.f)) {          // rare: newest-first => scores decay
            float wm = tm;
            wm = fmaxf(wm, __shfl_xor(wm, 1));
            wm = fmaxf(wm, __shfl_xor(wm, 2));
            wm = fmaxf(wm, __shfl_xor(wm, 4));
            wm = fmaxf(wm, __shfl_xor(wm, 8));
            wm = fmaxf(wm, __shfl_xor(wm, 16));
            wm = fmaxf(wm, __shfl_xor(wm, 32));
            float mn = fmaxf(m, wm);
            float sf = EXP2(m - mn);        // m=-1e30 -> 0
            m = mn;
            l *= sf;
            oacc[0] *= sf; oacc[1] *= sf; oacc[2] *= sf; oacc[3] *= sf;
        }
        float p[8];
#pragma unroll
        for (int r = 0; r < 8; ++r) p[r] = EXP2(sv[r] - m);
        l += ((p[0] + p[1]) + (p[2] + p[3])) + ((p[4] + p[5]) + (p[6] + p[7]));

        union { unsigned u32[4]; bf16x8 v8; } pf;
#pragma unroll
        for (int j = 0; j < 4; ++j)
            asm("v_cvt_pk_bf16_f32 %0, %1, %2" : "=v"(pf.u32[j]) : "v"(p[2 * j]), "v"(p[2 * j + 1]));

        oacc[0] = MFMA(vf0, pf.v8, oacc[0]);
        oacc[1] = MFMA(vf1, pf.v8, oacc[1]);
        oacc[2] = MFMA(vf2, pf.v8, oacc[2]);
        oacc[3] = MFMA(vf3, pf.v8, oacc[3]);
    };

    // software-pipelined: K of group i+1 in flight while computing group i
    KG cur = LOADK(c0_top);
    int c0 = c0_top;
    float c0f = (float)c0_top;
    while (c0 > c0_lo) {
        KG nxt = LOADK(c0 - 32);
        COMPUTE(cur, c0, c0f);
        cur = nxt;
        c0 -= 32;
        c0f -= 32.f;
    }
    COMPUTE(cur, c0, c0f);
}

// ---------------- main attention ----------------
__global__ __launch_bounds__(256, 4) void attn_mfma(
    const unsigned short* __restrict__ Qb, const unsigned short* __restrict__ Kb,
    const unsigned short* __restrict__ Vtb,
    const unsigned short* __restrict__ K1, const unsigned short* __restrict__ Vt1,
    const unsigned short* __restrict__ K2, const unsigned short* __restrict__ Vt2,
    const unsigned short* __restrict__ K3, const unsigned short* __restrict__ Vt3,
    const float* __restrict__ gam, float* __restrict__ out) {
    const int lane = threadIdx.x & 63;
    const int wid = threadIdx.x >> 6;
    // balance remap: h = low bits (2 heads per XCD for L2 locality);
    // q-tile = high bits (CU's resident blocks span the q range uniformly)
    const int h = blockIdx.x & 15;
    const int qt = blockIdx.x >> 4;
    const int Qs = (qt << 6) + wid * 16;
    const int g = lane >> 4;
    const int c = lane & 15;
    const int i_q = Qs + c;

    const float g0 = gam[0] * LOG2E, g1 = gam[1] * LOG2E;
    const float g2 = gam[2] * LOG2E, g3 = gam[3] * LOG2E;

    const unsigned short* Qrow = Qb + ((size_t)(h * NTOK + i_q)) * DD;
    bf16x8 q0 = *(const bf16x8*)(const void*)(Qrow + g * 8);
    bf16x8 q1 = *(const bf16x8*)(const void*)(Qrow + 32 + g * 8);

    f32x4 oacc[4];
#pragma unroll
    for (int t = 0; t < 4; ++t) oacc[t] = (f32x4){0.f, 0.f, 0.f, 0.f};
    float m = NEGF, l = 0.f;

    // level 0 (newest first; every query column has an active key in group 1)
    {
        int lo = Qs - 127; if (lo < 0) lo = 0; lo &= ~31;
        int top = (Qs + 15) & ~31;
        do_level<1, NTOK, true>(Kb + (size_t)h * NTOK * DD, Vtb + (size_t)h * DD * NTOK,
                                top, lo, Qs, g0, i_q, g, c, q0, q1, m, l, oacc);
    }
    {
        int cm = Qs - 120;                 // Qs+15-127-8
        if (cm >= 0)
            do_level<8, 1024, false>(K1 + (size_t)h * 1024 * DD, Vt1 + (size_t)h * DD * 1024,
                                     (cm / 8) & ~31, 0, Qs, g1, i_q, g, c, q0, q1, m, l, oacc);
    }
    {
        int cm = Qs - 176;                 // Qs+15-127-64
        if (cm >= 0)
            do_level<64, 128, false>(K2 + (size_t)h * 128 * DD, Vt2 + (size_t)h * DD * 128,
                                     (cm / 64) & ~31, 0, Qs, g2, i_q, g, c, q0, q1, m, l, oacc);
    }
    {
        int cm = Qs - 624;                 // Qs+15-127-512
        if (cm >= 0)
            do_level<512, 32, false>(K3 + (size_t)h * 32 * DD, Vt3 + (size_t)h * DD * 32,
                                     (cm / 512) & ~31, 0, Qs, g3, i_q, g, c, q0, q1, m, l, oacc);
    }

    // final l reduce over the 4 g-lanes of each query column
    float lt = l + __shfl_xor(l, 16);
    lt += __shfl_xor(lt, 32);
    float invl = 1.0f / fmaxf(lt, 1e-8f);

    float* orow = out + ((size_t)(h * NTOK + i_q)) * DD;
#pragma unroll
    for (int db = 0; db < 4; ++db) {
        float4 x;
        x.x = oacc[db][0] * invl;
        x.y = oacc[db][1] * invl;
        x.z = oacc[db][2] * invl;
        x.w = oacc[db][3] * invl;
        *(float4*)(orow + db * 16 + 4 * g) = x;
    }
}

extern "C" void kernel_launch(void* const* d_in, const int* in_sizes, int n_in,
                              void* d_out, int out_size, void* d_ws, size_t ws_size,
                              hipStream_t stream) {
    const float* q = (const float*)d_in[0];
    const float* k = (const float*)d_in[1];
    const float* v = (const float*)d_in[2];
    const float* gam = (const float*)d_in[3];
    float* out = (float*)d_out;

    char* w = (char*)d_ws;
    const size_t bigN = (size_t)NH * NTOK * DD * sizeof(unsigned short);
    unsigned short* Qb = (unsigned short*)w;            w += bigN;
    unsigned short* Kb = (unsigned short*)w;            w += bigN;
    unsigned short* Vtb = (unsigned short*)w;           w += bigN;
    unsigned short* K1 = (unsigned short*)w;            w += (size_t)NH * 1024 * DD * 2;
    unsigned short* Vt1 = (unsigned short*)w;           w += (size_t)NH * 1024 * DD * 2;
    unsigned short* K2 = (unsigned short*)w;            w += (size_t)NH * 128 * DD * 2;
    unsigned short* Vt2 = (unsigned short*)w;           w += (size_t)NH * 128 * DD * 2;
    unsigned short* K3 = (unsigned short*)w;            w += (size_t)NH * 32 * DD * 2;
    unsigned short* Vt3 = (unsigned short*)w;           w += (size_t)NH * 32 * DD * 2;

    int n8 = NH * NTOK * DD / 8;
    const float qscale = 0.125f * LOG2E;   // fold softmax scale + log2e into Q
    cvt_bf16<<<n8 / 256, 256, 0, stream>>>(q, Qb, qscale, n8);
    cvt_bf16<<<n8 / 256, 256, 0, stream>>>(k, Kb, 1.0f, n8);
    transpose_v<<<NH * (NTOK / 64), 256, 0, stream>>>(v, Vtb);
    pool1_kernel<<<NH * 1024 * DD / 256, 256, 0, stream>>>(k, v, K1, Vt1);
    pool2_kernel<<<NH * 128 * DD / 256, 256, 0, stream>>>(K1, Vt1, K2, Vt2);
    pool3_kernel<<<NH * 32 * DD / 256, 256, 0, stream>>>(K2, Vt2, K3, Vt3);

    attn_mfma<<<NH * (NTOK / 64), 256, 0, stream>>>(Qb, Kb, Vtb, K1, Vt1, K2, Vt2, K3, Vt3, gam, out);
}

// Round 5
// 203.037 us; speedup vs baseline: 13.3865x; 1.1841x over previous
//
#include <hip/hip_runtime.h>

#define NTOK 8192
#define NH 16
#define DD 64
#define NEGF -1e30f
#define LOG2E 1.4426950408889634f

typedef __attribute__((ext_vector_type(8))) short bf16x8;
typedef __attribute__((ext_vector_type(4))) float f32x4;

#define MFMA(a, b, c) __builtin_amdgcn_mfma_f32_16x16x32_bf16((a), (b), (c), 0, 0, 0)
#define EXP2(x) __builtin_amdgcn_exp2f(x)

static __device__ __forceinline__ unsigned short f2bf(float x) {
    union { float f; unsigned u; } c; c.f = x;
    unsigned r = (c.u + 0x7FFFu + ((c.u >> 16) & 1u)) >> 16;
    return (unsigned short)r;
}
static __device__ __forceinline__ float bf2f(unsigned short x) {
    union { unsigned u; float f; } c; c.u = ((unsigned)x) << 16;
    return c.f;
}

// ---------------- fp32 -> bf16 row-major convert (optional scale) ----------------
__global__ __launch_bounds__(256) void cvt_bf16(const float* __restrict__ s,
                                                unsigned short* __restrict__ d,
                                                float scale, int n8) {
    int t = blockIdx.x * blockDim.x + threadIdx.x;
    if (t >= n8) return;
    const float4* s4 = (const float4*)s;
    float4 a = s4[2 * (size_t)t], b = s4[2 * (size_t)t + 1];
    union { unsigned short u[8]; uint4 q; } o;
    o.u[0] = f2bf(a.x * scale); o.u[1] = f2bf(a.y * scale);
    o.u[2] = f2bf(a.z * scale); o.u[3] = f2bf(a.w * scale);
    o.u[4] = f2bf(b.x * scale); o.u[5] = f2bf(b.y * scale);
    o.u[6] = f2bf(b.z * scale); o.u[7] = f2bf(b.w * scale);
    *(uint4*)(d + 8 * (size_t)t) = o.q;
}

// ---------------- v (h,n,d) fp32 -> blocked vt[h][n>>5][d][n&31] bf16 ----------------
__global__ __launch_bounds__(256) void transpose_v(const float* __restrict__ v,
                                                   unsigned short* __restrict__ vt) {
    int h = blockIdx.x >> 7;
    int n0 = (blockIdx.x & 127) << 6;
    __shared__ unsigned short t[64][65];
    int tid = threadIdx.x;
    int col = tid & 63;      // d
    int rr = tid >> 6;       // 0..3
    const float* src = v + ((size_t)(h * NTOK + n0)) * DD;
#pragma unroll
    for (int r = 0; r < 16; ++r) {
        int row = rr + r * 4;   // n local
        t[col][row] = f2bf(src[(size_t)row * DD + col]);
    }
    __syncthreads();
    int d = tid >> 2, ch = tid & 3;
    union { unsigned short u[16]; uint4 q[2]; } tmp;
#pragma unroll
    for (int j = 0; j < 16; ++j) tmp.u[j] = t[d][ch * 16 + j];
    int b = (n0 >> 5) + (ch >> 1);
    unsigned short* dst = vt + ((size_t)(h * 256 + b)) * 2048 + d * 32 + (ch & 1) * 16;
    ((uint4*)dst)[0] = tmp.q[0];
    ((uint4*)dst)[1] = tmp.q[1];
}

// ---------------- level-1 pool: K1/V1 row-major + Vt1 blocked ----------------
__global__ __launch_bounds__(256) void pool1_kernel(const float* __restrict__ k, const float* __restrict__ v,
                                                    unsigned short* __restrict__ k1,
                                                    unsigned short* __restrict__ v1r,
                                                    unsigned short* __restrict__ vt1) {
    int tid = blockIdx.x * blockDim.x + threadIdx.x;   // NH*1024*64
    int d = tid & 63;
    int c = (tid >> 6) & 1023;
    int h = tid >> 16;
    size_t base = ((size_t)(h * NTOK + c * 8)) * DD + d;
    float ks = 0.f, vs = 0.f;
#pragma unroll
    for (int r = 0; r < 8; ++r) {
        ks += k[base + (size_t)r * DD];
        vs += v[base + (size_t)r * DD];
    }
    ks *= 0.125f; vs *= 0.125f;
    k1[((size_t)(h * 1024 + c)) * DD + d] = f2bf(ks);
    v1r[((size_t)(h * 1024 + c)) * DD + d] = f2bf(vs);
    vt1[((size_t)(h * 32 + (c >> 5))) * 2048 + d * 32 + (c & 31)] = f2bf(vs);
}

// ---------------- level-2 pool ----------------
__global__ __launch_bounds__(256) void pool2_kernel(const unsigned short* __restrict__ k1,
                                                    const unsigned short* __restrict__ v1r,
                                                    unsigned short* __restrict__ k2,
                                                    unsigned short* __restrict__ v2r,
                                                    unsigned short* __restrict__ vt2) {
    int tid = blockIdx.x * blockDim.x + threadIdx.x;   // NH*128*64
    int d = tid & 63;
    int c = (tid >> 6) & 127;
    int h = tid >> 13;
    float ks = 0.f, vs = 0.f;
#pragma unroll
    for (int j = 0; j < 8; ++j) {
        ks += bf2f(k1[((size_t)(h * 1024 + c * 8 + j)) * DD + d]);
        vs += bf2f(v1r[((size_t)(h * 1024 + c * 8 + j)) * DD + d]);
    }
    ks *= 0.125f; vs *= 0.125f;
    k2[((size_t)(h * 128 + c)) * DD + d] = f2bf(ks);
    v2r[((size_t)(h * 128 + c)) * DD + d] = f2bf(vs);
    vt2[((size_t)(h * 4 + (c >> 5))) * 2048 + d * 32 + (c & 31)] = f2bf(vs);
}

// ---------------- level-3 pool (16 real chunks, padded to 32) ----------------
__global__ __launch_bounds__(256) void pool3_kernel(const unsigned short* __restrict__ k2,
                                                    const unsigned short* __restrict__ v2r,
                                                    unsigned short* __restrict__ k3,
                                                    unsigned short* __restrict__ vt3) {
    int tid = blockIdx.x * blockDim.x + threadIdx.x;   // NH*32*64
    int d = tid & 63;
    int c = (tid >> 6) & 31;
    int h = tid >> 11;
    float ks = 0.f, vs = 0.f;
    if (c < 16) {
#pragma unroll
        for (int j = 0; j < 8; ++j) {
            ks += bf2f(k2[((size_t)(h * 128 + c * 8 + j)) * DD + d]);
            vs += bf2f(v2r[((size_t)(h * 128 + c * 8 + j)) * DD + d]);
        }
        ks *= 0.125f; vs *= 0.125f;
    }
    k3[((size_t)(h * 32 + c)) * DD + d] = f2bf(ks);
    vt3[(size_t)h * 2048 + d * 32 + c] = f2bf(vs);
}

// K fragments of one 32-key group (2 permuted 16-key tiles)
struct KG { bf16x8 k0, k1, k2, k3; };

// ---------------- per-level inner loop: 32 queries (2 tiles), 32 keys/iter ----------------
// Issue order per iter: [V_i] -> QK(K_i regs) -> [K_{i+1}] -> softmax -> PV.
// FIFO vmcnt then waits vmcnt(4) at QK (K arrived, V flying) and vmcnt(4) at PV.
template<int S, int NB, bool L0>
__device__ __forceinline__ void do_level(
    const unsigned short* __restrict__ Kh, const unsigned short* __restrict__ Vth,
    int c0_top, int c0_lo, int Qs, float gp, int g, int c,
    bf16x8 qa0, bf16x8 qa1, bf16x8 qb0, bf16x8 qb1,
    float& m, float& lA, float& lB, f32x4* oA, f32x4* oB) {

    const float gps = gp * (float)S;
    const int i_qA = Qs + c, i_qB = Qs + 16 + c;
    const float negfbA = gps * (float)(8 * g) + gp * (float)(S - 1) - gp * (float)i_qA;
    const float negfbB = negfbA - 16.f * gp;
    int c_allA = -0x40000000, c_allB = -0x40000000;
    if (!L0) {
        int numA = Qs - 128 - (S - 1);
        int numB = numA + 16;
        if (numA >= 0) c_allA = numA / S;
        if (numB >= 0) c_allB = numB / S;
    }
    const unsigned short* kb = Kh + ((size_t)(8 * (c >> 2) + (c & 3))) * DD + g * 8;
    const unsigned short* vb = Vth + c * 32 + g * 8;

    auto LOADK = [&](int c0) -> KG {
        KG r;
        const unsigned short* ka = kb + (size_t)c0 * DD;
        r.k0 = *(const bf16x8*)(const void*)(ka);
        r.k1 = *(const bf16x8*)(const void*)(ka + 32);
        r.k2 = *(const bf16x8*)(const void*)(ka + 4 * DD);
        r.k3 = *(const bf16x8*)(const void*)(ka + 4 * DD + 32);
        return r;
    };

    KG cur = LOADK(c0_top);
    float c0f = (float)c0_top;
    for (int c0 = c0_top; c0 >= c0_lo; c0 -= 32, c0f -= 32.f) {
        // V of this group: one contiguous 4KB block (fully-used cache lines)
        const unsigned short* va = vb + (size_t)(c0 >> 5) * 2048;
        bf16x8 vf0 = *(const bf16x8*)(const void*)(va);
        bf16x8 vf1 = *(const bf16x8*)(const void*)(va + 512);
        bf16x8 vf2 = *(const bf16x8*)(const void*)(va + 1024);
        bf16x8 vf3 = *(const bf16x8*)(const void*)(va + 1536);

        // QK^T on current K (registers) — waits only for K (older than V in FIFO)
        f32x4 z = {0.f, 0.f, 0.f, 0.f};
        f32x4 sAA = MFMA(cur.k1, qa1, MFMA(cur.k0, qa0, z));
        f32x4 sAB = MFMA(cur.k3, qa1, MFMA(cur.k2, qa0, z));
        f32x4 sBA = MFMA(cur.k1, qb1, MFMA(cur.k0, qb0, z));
        f32x4 sBB = MFMA(cur.k3, qb1, MFMA(cur.k2, qb0, z));

        // prefetch next K (issued AFTER V so PV's wait doesn't drain it)
        int cn = c0 - 32; if (cn < c0_lo) cn = c0_lo;
        KG nxt = LOADK(cn);

        // ---- bias + mask, tile A then tile B ----
        float svA[8], svB[8];
        bool fastA = L0 ? ((c0 >= Qs - 112) && (c0 + 31 <= Qs)) : (c0 + 31 <= c_allA);
        bool fastB = L0 ? ((c0 >= Qs - 96) && (c0 + 31 <= Qs + 16)) : (c0 + 31 <= c_allB);
        if (fastA) {
            float u0 = fmaf(gps, c0f, negfbA);
            svA[0] = sAA[0] + u0;
            svA[1] = sAA[1] + fmaf(gps, 1.f, u0);
            svA[2] = sAA[2] + fmaf(gps, 2.f, u0);
            svA[3] = sAA[3] + fmaf(gps, 3.f, u0);
            svA[4] = sAB[0] + fmaf(gps, 4.f, u0);
            svA[5] = sAB[1] + fmaf(gps, 5.f, u0);
            svA[6] = sAB[2] + fmaf(gps, 6.f, u0);
            svA[7] = sAB[3] + fmaf(gps, 7.f, u0);
        } else {
#pragma unroll
            for (int r = 0; r < 4; ++r) {
                int cA = c0 + 8 * g + r, cB = cA + 4;
                int jA = L0 ? cA : (cA * S + S - 1);
                int jB = L0 ? cB : (cB * S + S - 1);
                int dA = i_qA - jA, dB = i_qA - jB;
                bool aA = L0 ? ((unsigned)dA <= 127u) : (dA >= 128);
                bool aB = L0 ? ((unsigned)dB <= 127u) : (dB >= 128);
                svA[r]     = aA ? fmaf(-gp, (float)dA, sAA[r]) : NEGF;
                svA[r + 4] = aB ? fmaf(-gp, (float)dB, sAB[r]) : NEGF;
            }
        }
        if (fastB) {
            float u0 = fmaf(gps, c0f, negfbB);
            svB[0] = sBA[0] + u0;
            svB[1] = sBA[1] + fmaf(gps, 1.f, u0);
            svB[2] = sBA[2] + fmaf(gps, 2.f, u0);
            svB[3] = sBA[3] + fmaf(gps, 3.f, u0);
            svB[4] = sBB[0] + fmaf(gps, 4.f, u0);
            svB[5] = sBB[1] + fmaf(gps, 5.f, u0);
            svB[6] = sBB[2] + fmaf(gps, 6.f, u0);
            svB[7] = sBB[3] + fmaf(gps, 7.f, u0);
        } else {
#pragma unroll
            for (int r = 0; r < 4; ++r) {
                int cA = c0 + 8 * g + r, cB = cA + 4;
                int jA = L0 ? cA : (cA * S + S - 1);
                int jB = L0 ? cB : (cB * S + S - 1);
                int dA = i_qB - jA, dB = i_qB - jB;
                bool aA = L0 ? ((unsigned)dA <= 127u) : (dA >= 128);
                bool aB = L0 ? ((unsigned)dB <= 127u) : (dB >= 128);
                svB[r]     = aA ? fmaf(-gp, (float)dA, sBA[r]) : NEGF;
                svB[r + 4] = aB ? fmaf(-gp, (float)dB, sBB[r]) : NEGF;
            }
        }

        // wave-uniform deferred max (no per-group cross-lane reduce)
        float tm = fmaxf(
            fmaxf(fmaxf(fmaxf(svA[0], svA[1]), fmaxf(svA[2], svA[3])),
                  fmaxf(fmaxf(svA[4], svA[5]), fmaxf(svA[6], svA[7]))),
            fmaxf(fmaxf(fmaxf(svB[0], svB[1]), fmaxf(svB[2], svB[3])),
                  fmaxf(fmaxf(svB[4], svB[5]), fmaxf(svB[6], svB[7]))));
        if (__any(tm > m + 8.f)) {          // rare: newest-first => scores decay
            float wm = tm;
            wm = fmaxf(wm, __shfl_xor(wm, 1));
            wm = fmaxf(wm, __shfl_xor(wm, 2));
            wm = fmaxf(wm, __shfl_xor(wm, 4));
            wm = fmaxf(wm, __shfl_xor(wm, 8));
            wm = fmaxf(wm, __shfl_xor(wm, 16));
            wm = fmaxf(wm, __shfl_xor(wm, 32));
            float mn = fmaxf(m, wm);
            float sf = EXP2(m - mn);        // m=-1e30 -> 0
            m = mn;
            lA *= sf; lB *= sf;
            oA[0] *= sf; oA[1] *= sf; oA[2] *= sf; oA[3] *= sf;
            oB[0] *= sf; oB[1] *= sf; oB[2] *= sf; oB[3] *= sf;
        }

        union { unsigned u32[4]; bf16x8 v8; } pfA, pfB;
        {
            float p[8];
#pragma unroll
            for (int r = 0; r < 8; ++r) p[r] = EXP2(svA[r] - m);
            lA += ((p[0] + p[1]) + (p[2] + p[3])) + ((p[4] + p[5]) + (p[6] + p[7]));
#pragma unroll
            for (int j = 0; j < 4; ++j)
                asm("v_cvt_pk_bf16_f32 %0, %1, %2" : "=v"(pfA.u32[j]) : "v"(p[2 * j]), "v"(p[2 * j + 1]));
        }
        {
            float p[8];
#pragma unroll
            for (int r = 0; r < 8; ++r) p[r] = EXP2(svB[r] - m);
            lB += ((p[0] + p[1]) + (p[2] + p[3])) + ((p[4] + p[5]) + (p[6] + p[7]));
#pragma unroll
            for (int j = 0; j < 4; ++j)
                asm("v_cvt_pk_bf16_f32 %0, %1, %2" : "=v"(pfB.u32[j]) : "v"(p[2 * j]), "v"(p[2 * j + 1]));
        }

        // PV: V frags shared by both query tiles — waits vmcnt(4) (K_next flying)
        oA[0] = MFMA(vf0, pfA.v8, oA[0]);
        oB[0] = MFMA(vf0, pfB.v8, oB[0]);
        oA[1] = MFMA(vf1, pfA.v8, oA[1]);
        oB[1] = MFMA(vf1, pfB.v8, oB[1]);
        oA[2] = MFMA(vf2, pfA.v8, oA[2]);
        oB[2] = MFMA(vf2, pfB.v8, oB[2]);
        oA[3] = MFMA(vf3, pfA.v8, oA[3]);
        oB[3] = MFMA(vf3, pfB.v8, oB[3]);
        cur = nxt;
    }
}

// ---------------- main attention: 4 waves/block, 32 queries/wave ----------------
__global__ __launch_bounds__(256, 4) void attn_mfma(
    const unsigned short* __restrict__ Qb, const unsigned short* __restrict__ Kb,
    const unsigned short* __restrict__ Vtb,
    const unsigned short* __restrict__ K1, const unsigned short* __restrict__ Vt1,
    const unsigned short* __restrict__ K2, const unsigned short* __restrict__ Vt2,
    const unsigned short* __restrict__ K3, const unsigned short* __restrict__ Vt3,
    const float* __restrict__ gam, float* __restrict__ out) {
    const int lane = threadIdx.x & 63;
    const int wid = threadIdx.x >> 6;
    const int h = blockIdx.x & 15;      // 2 heads per XCD (L2 locality)
    const int qt = blockIdx.x >> 4;     // 0..63
    const int Qs = (qt << 7) + wid * 32;
    const int g = lane >> 4;
    const int c = lane & 15;

    const float g0 = gam[0] * LOG2E, g1 = gam[1] * LOG2E;
    const float g2 = gam[2] * LOG2E, g3 = gam[3] * LOG2E;

    const unsigned short* QrowA = Qb + ((size_t)(h * NTOK + Qs + c)) * DD;
    bf16x8 qa0 = *(const bf16x8*)(const void*)(QrowA + g * 8);
    bf16x8 qa1 = *(const bf16x8*)(const void*)(QrowA + 32 + g * 8);
    const unsigned short* QrowB = QrowA + 16 * DD;
    bf16x8 qb0 = *(const bf16x8*)(const void*)(QrowB + g * 8);
    bf16x8 qb1 = *(const bf16x8*)(const void*)(QrowB + 32 + g * 8);

    f32x4 oA[4], oB[4];
#pragma unroll
    for (int t = 0; t < 4; ++t) { oA[t] = (f32x4){0.f,0.f,0.f,0.f}; oB[t] = (f32x4){0.f,0.f,0.f,0.f}; }
    float m = NEGF, lA = 0.f, lB = 0.f;

    // level 0 (newest first)
    {
        int lo = Qs - 127; if (lo < 0) lo = 0; lo &= ~31;
        do_level<1, 256, true>(Kb + (size_t)h * NTOK * DD, Vtb + (size_t)h * 256 * 2048,
                               Qs, lo, Qs, g0, g, c, qa0, qa1, qb0, qb1, m, lA, lB, oA, oB);
    }
    {
        int cm = Qs - 104;                 // (Qs+31)-128-7
        if (cm >= 0)
            do_level<8, 32, false>(K1 + (size_t)h * 1024 * DD, Vt1 + (size_t)h * 32 * 2048,
                                   (cm / 8) & ~31, 0, Qs, g1, g, c, qa0, qa1, qb0, qb1, m, lA, lB, oA, oB);
    }
    {
        int cm = Qs - 160;                 // (Qs+31)-128-63
        if (cm >= 0)
            do_level<64, 4, false>(K2 + (size_t)h * 128 * DD, Vt2 + (size_t)h * 4 * 2048,
                                   (cm / 64) & ~31, 0, Qs, g2, g, c, qa0, qa1, qb0, qb1, m, lA, lB, oA, oB);
    }
    {
        int cm = Qs - 608;                 // (Qs+31)-128-511
        if (cm >= 0)
            do_level<512, 1, false>(K3 + (size_t)h * 32 * DD, Vt3 + (size_t)h * 2048,
                                    0, 0, Qs, g3, g, c, qa0, qa1, qb0, qb1, m, lA, lB, oA, oB);
    }

    // final l reduce over the 4 g-lanes of each query column
    float ltA = lA + __shfl_xor(lA, 16); ltA += __shfl_xor(ltA, 32);
    float ltB = lB + __shfl_xor(lB, 16); ltB += __shfl_xor(ltB, 32);
    float invA = 1.0f / fmaxf(ltA, 1e-8f);
    float invB = 1.0f / fmaxf(ltB, 1e-8f);

    float* orowA = out + ((size_t)(h * NTOK + Qs + c)) * DD;
    float* orowB = orowA + 16 * DD;
#pragma unroll
    for (int db = 0; db < 4; ++db) {
        float4 x;
        x.x = oA[db][0] * invA; x.y = oA[db][1] * invA;
        x.z = oA[db][2] * invA; x.w = oA[db][3] * invA;
        *(float4*)(orowA + db * 16 + 4 * g) = x;
        float4 y;
        y.x = oB[db][0] * invB; y.y = oB[db][1] * invB;
        y.z = oB[db][2] * invB; y.w = oB[db][3] * invB;
        *(float4*)(orowB + db * 16 + 4 * g) = y;
    }
}

extern "C" void kernel_launch(void* const* d_in, const int* in_sizes, int n_in,
                              void* d_out, int out_size, void* d_ws, size_t ws_size,
                              hipStream_t stream) {
    const float* q = (const float*)d_in[0];
    const float* k = (const float*)d_in[1];
    const float* v = (const float*)d_in[2];
    const float* gam = (const float*)d_in[3];
    float* out = (float*)d_out;

    char* w = (char*)d_ws;
    const size_t bigN = (size_t)NH * NTOK * DD * sizeof(unsigned short);
    unsigned short* Qb  = (unsigned short*)w;  w += bigN;
    unsigned short* Kb  = (unsigned short*)w;  w += bigN;
    unsigned short* Vtb = (unsigned short*)w;  w += bigN;                       // blocked
    unsigned short* K1  = (unsigned short*)w;  w += (size_t)NH * 1024 * DD * 2;
    unsigned short* V1r = (unsigned short*)w;  w += (size_t)NH * 1024 * DD * 2;
    unsigned short* Vt1 = (unsigned short*)w;  w += (size_t)NH * 1024 * DD * 2; // blocked
    unsigned short* K2  = (unsigned short*)w;  w += (size_t)NH * 128 * DD * 2;
    unsigned short* V2r = (unsigned short*)w;  w += (size_t)NH * 128 * DD * 2;
    unsigned short* Vt2 = (unsigned short*)w;  w += (size_t)NH * 128 * DD * 2;  // blocked
    unsigned short* K3  = (unsigned short*)w;  w += (size_t)NH * 32 * DD * 2;
    unsigned short* Vt3 = (unsigned short*)w;  w += (size_t)NH * 32 * DD * 2;   // blocked

    int n8 = NH * NTOK * DD / 8;
    const float qscale = 0.125f * LOG2E;   // fold softmax scale + log2e into Q
    cvt_bf16<<<n8 / 256, 256, 0, stream>>>(q, Qb, qscale, n8);
    cvt_bf16<<<n8 / 256, 256, 0, stream>>>(k, Kb, 1.0f, n8);
    transpose_v<<<NH * (NTOK / 64), 256, 0, stream>>>(v, Vtb);
    pool1_kernel<<<NH * 1024 * DD / 256, 256, 0, stream>>>(k, v, K1, V1r, Vt1);
    pool2_kernel<<<NH * 128 * DD / 256, 256, 0, stream>>>(K1, V1r, K2, V2r, Vt2);
    pool3_kernel<<<NH * 32 * DD / 256, 256, 0, stream>>>(K2, V2r, K3, Vt3);

    attn_mfma<<<NH * 64, 256, 0, stream>>>(Qb, Kb, Vtb, K1, Vt1, K2, Vt2, K3, Vt3, gam, out);
}